// Round 1
// baseline (9751.473 us; speedup 1.0000x reference)
//
#include <hip/hip_runtime.h>
#include <hip/hip_bf16.h>
#include <math.h>

#define EPS 1e-5f
#define XAS 97
#define QS 17
#define SS 65

__device__ __forceinline__ float gelu_f(float x){
    return 0.5f*x*(1.0f+erff(x*0.7071067811865475f));
}
__device__ __forceinline__ float sigmoid_f(float x){
    return 1.0f/(1.0f+__expf(-x));
}
// row (wi*64+n) -> b*32768 + voxel   (window order b,d,h,w ; in-window order wd,wh,ww)
__device__ __forceinline__ int row_to_bv(int r){
    int wi = r >> 6, n = r & 63;
    int b = wi >> 9, rem = wi & 511;
    int zd = rem >> 6, yh = (rem >> 3) & 7, xw = rem & 7;
    int wz = n >> 4, wy = (n >> 2) & 3, wx = n & 3;
    int Dz = (zd<<2)+wz, Hy = (yh<<2)+wy, Wx = (xw<<2)+wx;
    return (b<<15) + (Dz<<10) + (Hy<<5) + Wx;
}
__device__ __forceinline__ int relidx(int i,int j){
    int zi=i>>4, yi=(i>>2)&3, xi=i&3;
    int zj=j>>4, yj=(j>>2)&3, xj=j&3;
    return ((zi-zj+3)*7+(yi-yj+3))*7+(xi-xj+3);
}

// ---------------- K1: dual GEMM (192->96 & 192->192) + both LayerNorms ----------------
__global__ __launch_bounds__(256) void k1_pre(const float* __restrict__ x,
    const float* __restrict__ w1, const float* __restrict__ b1,
    const float* __restrict__ g1, const float* __restrict__ bb1,
    const float* __restrict__ w2, const float* __restrict__ b2,
    const float* __restrict__ g2, const float* __restrict__ bb2,
    float* __restrict__ xa, float* __restrict__ vol)
{
    __shared__ float xs[32*192];
    __shared__ float ws[32*288];
    int tid = threadIdx.x;
    int row0 = blockIdx.x * 32;
    for(int i=tid;i<32*192;i+=256) xs[i] = x[(size_t)row0*192 + i];
    float acc[4][9]={};
    int cbase = tid & 31;
    int rbase = (tid >> 5) << 2;
    for(int k0=0;k0<192;k0+=32){
        __syncthreads();
        for(int i=tid;i<32*288;i+=256){
            int kk=i/288, cc=i-kk*288;
            int kg=k0+kk;
            ws[i] = (cc<96)? w1[kg*96+cc] : w2[kg*192+(cc-96)];
        }
        __syncthreads();
        for(int kk=0;kk<32;kk++){
            float a0=xs[(rbase+0)*192+k0+kk];
            float a1=xs[(rbase+1)*192+k0+kk];
            float a2=xs[(rbase+2)*192+k0+kk];
            float a3=xs[(rbase+3)*192+k0+kk];
            #pragma unroll
            for(int j=0;j<9;j++){
                float wv=ws[kk*288+cbase+32*j];
                acc[0][j]+=a0*wv; acc[1][j]+=a1*wv; acc[2][j]+=a2*wv; acc[3][j]+=a3*wv;
            }
        }
    }
    __syncthreads();
    #pragma unroll
    for(int a=0;a<4;a++){
        #pragma unroll
        for(int j=0;j<9;j++){
            int cc=cbase+32*j;
            ws[(rbase+a)*288+cc]=acc[a][j] + ((cc<96)? b1[cc] : b2[cc-96]);
        }
    }
    __syncthreads();
    int lr = tid>>3, part = tid&7;
    int r = row0+lr;
    // LN attention part (96)
    {
        float s=0.f, ss=0.f;
        for(int c=part*12;c<part*12+12;c++){ float v=ws[lr*288+c]; s+=v; ss+=v*v; }
        for(int o=1;o<8;o<<=1){ s+=__shfl_xor(s,o); ss+=__shfl_xor(ss,o); }
        float m=s*(1.f/96.f), var=ss*(1.f/96.f)-m*m, rstd=rsqrtf(var+EPS);
        for(int c=part*12;c<part*12+12;c++){
            xa[(size_t)r*96+c]=(ws[lr*288+c]-m)*rstd*g1[c]+bb1[c];
        }
    }
    // LN cnn part (192) -> scatter to volume (NDHWC)
    {
        float s=0.f, ss=0.f;
        for(int c=96+part*24;c<96+part*24+24;c++){ float v=ws[lr*288+c]; s+=v; ss+=v*v; }
        for(int o=1;o<8;o<<=1){ s+=__shfl_xor(s,o); ss+=__shfl_xor(ss,o); }
        float m=s*(1.f/192.f), var=ss*(1.f/192.f)-m*m, rstd=rsqrtf(var+EPS);
        int bv = row_to_bv(r);
        for(int c=part*24;c<part*24+24;c++){
            vol[(size_t)bv*192+c]=(ws[lr*288+96+c]-m)*rstd*g2[c]+bb2[c];
        }
    }
}

// ---------------- K2: depthwise 3x3x3 conv, NDHWC, slide along W ----------------
__global__ __launch_bounds__(192) void k2_dwconv(const float* __restrict__ vin,
        const float* __restrict__ wd_, const float* __restrict__ bd,
        float* __restrict__ vout)
{
    int c=threadIdx.x;
    int blk=blockIdx.x;
    int Hy=blk&31, Dz=(blk>>5)&31, b=blk>>10;
    float wreg[27];
    #pragma unroll
    for(int t=0;t<27;t++) wreg[t]=wd_[c*27+t];
    float bias=bd[c];
    const float* base=vin + ((size_t)b<<15)*192;
    int voff[9]; bool vld[9];
    #pragma unroll
    for(int i=0;i<9;i++){
        int zz=Dz+i/3-1, yy=Hy+i%3-1;
        vld[i]=(zz>=0&&zz<32&&yy>=0&&yy<32);
        voff[i]=(zz<<10)+(yy<<5);
    }
    float prv[9],cur[9],nxt[9];
    #pragma unroll
    for(int i=0;i<9;i++){
        prv[i]=0.f;
        cur[i]= vld[i]? base[(size_t)(voff[i])*192+c]   : 0.f;
        nxt[i]= vld[i]? base[(size_t)(voff[i]+1)*192+c] : 0.f;
    }
    size_t obase=((size_t)((b<<15)+(Dz<<10)+(Hy<<5)))*192 + c;
    for(int wx=0;wx<32;wx++){
        float o=bias;
        #pragma unroll
        for(int i=0;i<9;i++) o += prv[i]*wreg[i*3] + cur[i]*wreg[i*3+1] + nxt[i]*wreg[i*3+2];
        vout[obase + (size_t)wx*192] = o;
        #pragma unroll
        for(int i=0;i<9;i++){ prv[i]=cur[i]; cur[i]=nxt[i]; }
        int wn=wx+2;
        #pragma unroll
        for(int i=0;i<9;i++) nxt[i]=(vld[i]&&wn<32)? base[(size_t)(voff[i]+wn)*192+c] : 0.f;
    }
}

// ---------------- K3: instance-norm partial sums over spatial (per b,c) ----------------
__global__ __launch_bounds__(192) void k3_stats(const float* __restrict__ v,
      float* __restrict__ sum, float* __restrict__ sumsq)
{
    int c=threadIdx.x;
    int chunk=blockIdx.x, b=blockIdx.y;
    float s=0.f,ss=0.f;
    const float* p = v + (((size_t)b<<15) + (size_t)chunk*256)*192 + c;
    for(int i=0;i<256;i++){ float t=p[(size_t)i*192]; s+=t; ss+=t*t; }
    atomicAdd(&sum[b*192+c], s);
    atomicAdd(&sumsq[b*192+c], ss);
}

__global__ void k_finalize(const float* __restrict__ sum, const float* __restrict__ sumsq,
                           float* __restrict__ mean, float* __restrict__ rstd, int n, float inv)
{
    int i = blockIdx.x*blockDim.x + threadIdx.x;
    if(i<n){ float m=sum[i]*inv; float v=sumsq[i]*inv - m*m; mean[i]=m; rstd[i]=rsqrtf(v+EPS); }
}

// ---------------- K4: in-place inorm+gelu + pooled partials ----------------
__global__ __launch_bounds__(192) void k4_apply(float* __restrict__ v,
      const float* __restrict__ mean, const float* __restrict__ rstd, float* __restrict__ pooled)
{
    int c=threadIdx.x; int chunk=blockIdx.x, b=blockIdx.y;
    float m=mean[b*192+c], r=rstd[b*192+c];
    float s=0.f;
    float* p = v + (((size_t)b<<15)+(size_t)chunk*256)*192 + c;
    for(int i=0;i<256;i++){
        float t=(p[(size_t)i*192]-m)*r;
        t=gelu_f(t);
        p[(size_t)i*192]=t; s+=t;
    }
    atomicAdd(&pooled[b*192+c], s);
}

// ---------------- K4b: channel-interaction MLP -> sigmoid gate ----------------
__global__ __launch_bounds__(128) void k4b_gate(const float* __restrict__ pooled,
   const float* __restrict__ w1,const float* __restrict__ b1,
   const float* __restrict__ w2,const float* __restrict__ b2, float* __restrict__ gate)
{
    __shared__ float pm[192];
    __shared__ float h[24];
    int b=blockIdx.x, t=threadIdx.x;
    for(int i=t;i<192;i+=128) pm[i]=pooled[b*192+i]*(1.f/32768.f);
    __syncthreads();
    if(t<24){ float a=b1[t]; for(int k=0;k<192;k++) a+=pm[k]*w1[k*24+t]; h[t]=gelu_f(a); }
    __syncthreads();
    if(t<96){ float a=b2[t]; for(int j=0;j<24;j++) a+=h[j]*w2[j*96+t]; gate[b*96+t]=sigmoid_f(a); }
}

// ---------------- Kqkv: QKV GEMM (K=96), q*0.25 and v*gate folded, bf16 out ----------------
__global__ __launch_bounds__(256) void kqkv(const float* __restrict__ xa,
    const float* __restrict__ w, const float* __restrict__ bias,
    const float* __restrict__ gate, __hip_bfloat16* __restrict__ qkv)
{
    __shared__ float xs[32*96];
    __shared__ float ws[32*288];
    int tid=threadIdx.x; int row0=blockIdx.x*32;
    for(int i=tid;i<32*96;i+=256) xs[i]=xa[(size_t)row0*96+i];
    float acc[4][9]={};
    int cbase=tid&31, rbase=(tid>>5)<<2;
    for(int k0=0;k0<96;k0+=32){
        __syncthreads();
        for(int i=tid;i<32*288;i+=256){int kk=i/288,cc=i-kk*288; ws[i]=w[(k0+kk)*288+cc];}
        __syncthreads();
        for(int kk=0;kk<32;kk++){
            float a0=xs[(rbase+0)*96+k0+kk],a1=xs[(rbase+1)*96+k0+kk],
                  a2=xs[(rbase+2)*96+k0+kk],a3=xs[(rbase+3)*96+k0+kk];
            #pragma unroll
            for(int j=0;j<9;j++){
                float wv=ws[kk*288+cbase+32*j];
                acc[0][j]+=a0*wv;acc[1][j]+=a1*wv;acc[2][j]+=a2*wv;acc[3][j]+=a3*wv;
            }
        }
    }
    #pragma unroll
    for(int a=0;a<4;a++){
        int row=row0+rbase+a; int wi=row>>6, n=row&63, b=row>>15;
        #pragma unroll
        for(int j=0;j<9;j++){
            int col=cbase+32*j;
            float v=acc[a][j]+bias[col];
            int which=col/96, rem=col-which*96;
            int hh=rem>>4, e=rem&15;
            if(which==0) v*=0.25f;
            else if(which==2) v*=gate[b*96+rem];
            qkv[((size_t)(wi*18+which*6+hh)<<10) + (n<<4) + e]=__float2bfloat16(v);
        }
    }
}

// ---------------- K6: windowed attention (per window, loop heads) ----------------
__global__ __launch_bounds__(256) void k6_attn(const __hip_bfloat16* __restrict__ qkv,
    const float* __restrict__ rpb, float* __restrict__ ato)
{
    __shared__ float sq[64*QS], sk[64*QS], sv[64*QS];
    __shared__ float sS[64*SS];
    int tid=threadIdx.x;
    int wi=blockIdx.x;
    for(int h=0;h<6;h++){
        __syncthreads();
        for(int i=tid;i<3*1024;i+=256){
            int which=i>>10, r=i&1023; int n=r>>4, e=r&15;
            float val=__bfloat162float(qkv[((size_t)(wi*18+which*6+h)<<10) + r]);
            if(which==0) sq[n*QS+e]=val; else if(which==1) sk[n*QS+e]=val; else sv[n*QS+e]=val;
        }
        __syncthreads();
        {   // S = qk^T + bias : 4x4 tiles
            int ti=tid>>4, tj=tid&15;
            int i0=ti*4, j0=tj*4;
            float a[4][4]={};
            #pragma unroll
            for(int e=0;e<16;e++){
                float qv[4], kv[4];
                #pragma unroll
                for(int ii=0;ii<4;ii++) qv[ii]=sq[(i0+ii)*QS+e];
                #pragma unroll
                for(int jj=0;jj<4;jj++) kv[jj]=sk[(j0+jj)*QS+e];
                #pragma unroll
                for(int ii=0;ii<4;ii++)
                    #pragma unroll
                    for(int jj=0;jj<4;jj++) a[ii][jj]+=qv[ii]*kv[jj];
            }
            #pragma unroll
            for(int ii=0;ii<4;ii++)
                #pragma unroll
                for(int jj=0;jj<4;jj++)
                    sS[(i0+ii)*SS+j0+jj]=a[ii][jj]+rpb[relidx(i0+ii,j0+jj)*6+h];
        }
        __syncthreads();
        {   // softmax rows (4 lanes per row)
            int i=tid>>2, j0=(tid&3)<<4;
            float mx=-1e30f;
            for(int jj=0;jj<16;jj++) mx=fmaxf(mx,sS[i*SS+j0+jj]);
            for(int o=1;o<4;o<<=1) mx=fmaxf(mx,__shfl_xor(mx,o));
            float sum=0.f;
            for(int jj=0;jj<16;jj++){float p=__expf(sS[i*SS+j0+jj]-mx); sS[i*SS+j0+jj]=p; sum+=p;}
            for(int o=1;o<4;o<<=1) sum+=__shfl_xor(sum,o);
            float inv=1.f/sum;
            for(int jj=0;jj<16;jj++) sS[i*SS+j0+jj]*=inv;
        }
        __syncthreads();
        {   // O = P @ v
            int i=tid&63, e0=(tid>>6)<<2;
            float o0=0.f,o1=0.f,o2=0.f,o3=0.f;
            for(int j=0;j<64;j++){
                float p=sS[i*SS+j];
                o0+=p*sv[j*QS+e0];o1+=p*sv[j*QS+e0+1];o2+=p*sv[j*QS+e0+2];o3+=p*sv[j*QS+e0+3];
            }
            float* dst=&ato[((size_t)(wi*64+i))*96 + (h<<4) + e0];
            dst[0]=o0;dst[1]=o1;dst[2]=o2;dst[3]=o3;
        }
    }
}

// ---------------- K5: 1x1 conv 192->96 (post-gelu volume) ----------------
__global__ __launch_bounds__(256) void k5_pj(const float* __restrict__ vin,
    const float* __restrict__ w, const float* __restrict__ bias, float* __restrict__ out)
{
    __shared__ float xs[32*192];
    __shared__ float ws[32*96];
    int tid=threadIdx.x; int row0=blockIdx.x*32;
    for(int i=tid;i<32*192;i+=256) xs[i]=vin[(size_t)row0*192+i];
    float acc[4][3]={};
    int cbase=tid&31, rbase=(tid>>5)<<2;
    for(int k0=0;k0<192;k0+=32){
        __syncthreads();
        for(int i=tid;i<32*96;i+=256){ int kk=i/96, cc=i-kk*96; ws[i]=w[(k0+kk)*96+cc]; }
        __syncthreads();
        for(int kk=0;kk<32;kk++){
            float a0=xs[(rbase+0)*192+k0+kk], a1=xs[(rbase+1)*192+k0+kk],
                  a2=xs[(rbase+2)*192+k0+kk], a3=xs[(rbase+3)*192+k0+kk];
            #pragma unroll
            for(int j=0;j<3;j++){
                float wv=ws[kk*96+cbase+32*j];
                acc[0][j]+=a0*wv; acc[1][j]+=a1*wv; acc[2][j]+=a2*wv; acc[3][j]+=a3*wv;
            }
        }
    }
    #pragma unroll
    for(int a=0;a<4;a++){
        #pragma unroll
        for(int j=0;j<3;j++){
            int cc=cbase+32*j;
            out[(size_t)(row0+rbase+a)*96+cc]=acc[a][j]+bias[cc];
        }
    }
}

// ---------------- K7a: spatial-interaction conv1 (96->12) + stats ----------------
__global__ __launch_bounds__(192) void k7a_si(const float* __restrict__ ato,
    const float* __restrict__ w1, const float* __restrict__ b1,
    float* __restrict__ si12, float* __restrict__ siSum, float* __restrict__ siSumsq)
{
    __shared__ float sa[64*XAS];
    __shared__ float sw[96*12];
    __shared__ float red[24];
    int tid=threadIdx.x, wi=blockIdx.x, b=wi>>9;
    for(int i=tid;i<64*96;i+=192){ int n=i/96,c=i-n*96; sa[n*XAS+c]=ato[((size_t)(wi*64+n))*96+c]; }
    for(int i=tid;i<96*12;i+=192) sw[i]=w1[i];
    if(tid<24) red[tid]=0.f;
    __syncthreads();
    #pragma unroll
    for(int j=0;j<4;j++){
        int o=tid+192*j; int n=o/12, cc=o-n*12;
        float a=b1[cc];
        for(int k=0;k<96;k++) a+=sa[n*XAS+k]*sw[k*12+cc];
        atomicAdd(&red[cc],a);
        atomicAdd(&red[12+cc],a*a);
        int bv=row_to_bv(wi*64+n);
        si12[(size_t)bv*12+cc]=a;
    }
    __syncthreads();
    if(tid<12){ atomicAdd(&siSum[b*12+tid],red[tid]); atomicAdd(&siSumsq[b*12+tid],red[12+tid]); }
}

// ---------------- K7d: inorm+gelu on si12, conv2 (12->1), sigmoid ----------------
__global__ __launch_bounds__(256) void k7d_sig(const float* __restrict__ si12,
  const float* __restrict__ mean, const float* __restrict__ rstd,
  const float* __restrict__ w2, const float* __restrict__ b2, float* __restrict__ sig)
{
    int bv=blockIdx.x*256+threadIdx.x;
    int b=bv>>15;
    float a=b2[0];
    #pragma unroll
    for(int c=0;c<12;c++){
        float t=(si12[(size_t)bv*12+c]-mean[b*12+c])*rstd[b*12+c];
        a+=gelu_f(t)*w2[c];
    }
    sig[bv]=sigmoid_f(a);
}

// ---------------- K8: stats of sigmoid(si)*PJ (per b,c of 96) ----------------
__global__ __launch_bounds__(192) void k8_gstats(const float* __restrict__ pj,
   const float* __restrict__ sig, float* __restrict__ gSum, float* __restrict__ gSumsq)
{
    int tid=threadIdx.x; int c=tid%96, vh=tid/96;
    int chunk=blockIdx.x, b=blockIdx.y;
    float s=0.f,ss=0.f;
    for(int i=0;i<128;i++){
        int v=chunk*256 + i*2 + vh;
        int bv=(b<<15)+v;
        float t=sig[bv]*pj[(size_t)bv*96+c];
        s+=t; ss+=t*t;
    }
    atomicAdd(&gSum[b*96+c],s); atomicAdd(&gSumsq[b*96+c],ss);
}

// ---------------- K9: LN(attn) + gated-inorm gather + final 192x192 projection ----------------
__global__ __launch_bounds__(256) void k9_out(const float* __restrict__ ato,
  const float* __restrict__ pj, const float* __restrict__ sig,
  const float* __restrict__ gMean, const float* __restrict__ gRstd,
  const float* __restrict__ ga, const float* __restrict__ bba,
  const float* __restrict__ wp, const float* __restrict__ bp,
  float* __restrict__ out)
{
    __shared__ float u[32*192];
    __shared__ float ws[32*192];
    int tid=threadIdx.x; int row0=blockIdx.x*32;
    for(int i=tid;i<32*96;i+=256){ int rr=i/96,c=i-rr*96; u[rr*192+c]=ato[(size_t)(row0+rr)*96+c]; }
    __syncthreads();
    {
        int rr=tid>>3, part=tid&7;
        int r=row0+rr;
        int bv=row_to_bv(r); int b=bv>>15;
        float sg=sig[bv];
        for(int c=part*12;c<part*12+12;c++){
            float t=sg*pj[(size_t)bv*96+c];
            u[rr*192+96+c]=(t-gMean[b*96+c])*gRstd[b*96+c];
        }
        float s=0.f,ss=0.f;
        for(int c=part*12;c<part*12+12;c++){ float v2=u[rr*192+c]; s+=v2; ss+=v2*v2; }
        for(int o=1;o<8;o<<=1){ s+=__shfl_xor(s,o); ss+=__shfl_xor(ss,o); }
        float m=s*(1.f/96.f), var=ss*(1.f/96.f)-m*m, rstd=rsqrtf(var+EPS);
        for(int c=part*12;c<part*12+12;c++){
            u[rr*192+c]=(u[rr*192+c]-m)*rstd*ga[c]+bba[c];
        }
    }
    float acc[4][6]={};
    int cbase=tid&31, rbase=(tid>>5)<<2;
    for(int k0=0;k0<192;k0+=32){
        __syncthreads();
        for(int i=tid;i<32*192;i+=256){ int kk=i/192,cc=i-kk*192; ws[i]=wp[(k0+kk)*192+cc]; }
        __syncthreads();
        for(int kk=0;kk<32;kk++){
            float a0=u[(rbase+0)*192+k0+kk],a1=u[(rbase+1)*192+k0+kk],
                  a2=u[(rbase+2)*192+k0+kk],a3=u[(rbase+3)*192+k0+kk];
            #pragma unroll
            for(int j=0;j<6;j++){
                float wv=ws[kk*192+cbase+32*j];
                acc[0][j]+=a0*wv;acc[1][j]+=a1*wv;acc[2][j]+=a2*wv;acc[3][j]+=a3*wv;
            }
        }
    }
    #pragma unroll
    for(int a=0;a<4;a++){
        #pragma unroll
        for(int j=0;j<6;j++){
            int cc=cbase+32*j;
            out[(size_t)(row0+rbase+a)*192+cc]=acc[a][j]+bp[cc];
        }
    }
}

extern "C" void kernel_launch(void* const* d_in, const int* in_sizes, int n_in,
                              void* d_out, int out_size, void* d_ws, size_t ws_size,
                              hipStream_t stream)
{
    const float* x      =(const float*)d_in[0];
    const float* w_pattn=(const float*)d_in[1];
    const float* b_pattn=(const float*)d_in[2];
    const float* g_aln  =(const float*)d_in[3];
    const float* b_aln  =(const float*)d_in[4];
    const float* w_pcnn =(const float*)d_in[5];
    const float* b_pcnn =(const float*)d_in[6];
    const float* g_cln  =(const float*)d_in[7];
    const float* b_cln  =(const float*)d_in[8];
    const float* dw_w   =(const float*)d_in[9];
    const float* dw_b   =(const float*)d_in[10];
    const float* ci_w1  =(const float*)d_in[11];
    const float* ci_b1  =(const float*)d_in[12];
    const float* ci_w2  =(const float*)d_in[13];
    const float* ci_b2  =(const float*)d_in[14];
    const float* pj_w   =(const float*)d_in[15];
    const float* pj_b   =(const float*)d_in[16];
    const float* qkv_w  =(const float*)d_in[17];
    const float* qkv_b  =(const float*)d_in[18];
    const float* si_w1  =(const float*)d_in[19];
    const float* si_b1  =(const float*)d_in[20];
    const float* si_w2  =(const float*)d_in[21];
    const float* si_b2  =(const float*)d_in[22];
    const float* g_anorm=(const float*)d_in[23];
    const float* b_anorm=(const float*)d_in[24];
    const float* w_proj =(const float*)d_in[25];
    const float* b_proj =(const float*)d_in[26];
    const float* rpb    =(const float*)d_in[27];
    (void)in_sizes; (void)n_in; (void)out_size; (void)ws_size;

    float* ws  =(float*)d_ws;
    float* vol =(float*)d_out;            // post-dwconv volume lives in d_out until K9
    // ws float offsets (total 37,748,736 floats = 151 MB):
    float* XA   = ws;                     // [0, 12,582,912)  -> later reused as ATO
    float* VOLA = ws + 12582912;          // [12,582,912, 37,748,736) : LN'd cnn volume
    __hip_bfloat16* QKV = (__hip_bfloat16*)(ws + 12582912);  // overlays dead VOLA after K2
    float* PJ   = ws + 12582912;          // overlays dead QKV after K6
    float* SI12 = ws + 25165824;          // [25,165,824, 26,738,688)
    float* SIG  = ws + 26738688;          // [26,738,688, 26,869,760)
    float* Z0   = ws + 31457280;          // zeroed accumulators (3168 floats)
    float* IN_SUM   = Z0;        float* IN_SUMSQ = Z0+768;
    float* POOLED   = Z0+1536;
    float* SI_SUM   = Z0+2304;   float* SI_SUMSQ = Z0+2352;
    float* G_SUM    = Z0+2400;   float* G_SUMSQ  = Z0+2784;
    float* NZ   = ws + 31460448;
    float* IN_MEAN  = NZ;        float* IN_RSTD  = NZ+768;
    float* GATE     = NZ+1536;
    float* SI_MEAN  = NZ+1920;   float* SI_RSTD  = NZ+1968;
    float* G_MEAN   = NZ+2016;   float* G_RSTD   = NZ+2400;

    // 1. dual GEMM + LNs
    k1_pre<<<4096,256,0,stream>>>(x,w_pattn,b_pattn,g_aln,b_aln,
                                  w_pcnn,b_pcnn,g_cln,b_cln,XA,VOLA);
    // 2. depthwise conv -> d_out
    k2_dwconv<<<4096,192,0,stream>>>(VOLA,dw_w,dw_b,vol);
    // zero accumulators (VOLA now dead; Z0 sits in its tail)
    hipMemsetAsync((void*)Z0, 0, 3168*sizeof(float), stream);
    // 3. instance norm stats + finalize
    k3_stats<<<dim3(128,4),192,0,stream>>>(vol,IN_SUM,IN_SUMSQ);
    k_finalize<<<3,256,0,stream>>>(IN_SUM,IN_SUMSQ,IN_MEAN,IN_RSTD,768,1.f/32768.f);
    // 4. in-place inorm+gelu + pooled ; gate MLP
    k4_apply<<<dim3(128,4),192,0,stream>>>(vol,IN_MEAN,IN_RSTD,POOLED);
    k4b_gate<<<4,128,0,stream>>>(POOLED,ci_w1,ci_b1,ci_w2,ci_b2,GATE);
    // 5. QKV GEMM (bf16 out, gate/scale folded)
    kqkv<<<4096,256,0,stream>>>(XA,qkv_w,qkv_b,GATE,QKV);
    // 6. attention (writes ATO over dead XA)
    k6_attn<<<2048,256,0,stream>>>(QKV,rpb,XA);
    // 7. 1x1 conv 192->96 (PJ overlays dead QKV head)
    k5_pj<<<4096,256,0,stream>>>(vol,pj_w,pj_b,PJ);
    // 8. spatial-interaction path
    k7a_si<<<2048,192,0,stream>>>(XA,si_w1,si_b1,SI12,SI_SUM,SI_SUMSQ);
    k_finalize<<<1,64,0,stream>>>(SI_SUM,SI_SUMSQ,SI_MEAN,SI_RSTD,48,1.f/32768.f);
    k7d_sig<<<512,256,0,stream>>>(SI12,SI_MEAN,SI_RSTD,si_w2,si_b2,SIG);
    // 9. gated-cnn instance norm stats
    k8_gstats<<<dim3(128,4),192,0,stream>>>(PJ,SIG,G_SUM,G_SUMSQ);
    k_finalize<<<2,256,0,stream>>>(G_SUM,G_SUMSQ,G_MEAN,G_RSTD,384,1.f/32768.f);
    // 10. final fused LN + gated inorm + projection
    k9_out<<<4096,256,0,stream>>>(XA,PJ,SIG,G_MEAN,G_RSTD,
                                  g_anorm,b_anorm,w_proj,b_proj,vol);
}

// Round 2
// 9563.354 us; speedup vs baseline: 1.0197x; 1.0197x over previous
//
#include <hip/hip_runtime.h>
#include <hip/hip_bf16.h>
#include <math.h>

#define EPS 1e-5f
#define XAS 97
#define QS 17
#define SS 65

__device__ __forceinline__ float gelu_f(float x){
    return 0.5f*x*(1.0f+erff(x*0.7071067811865475f));
}
__device__ __forceinline__ float sigmoid_f(float x){
    return 1.0f/(1.0f+__expf(-x));
}
// row (wi*64+n) -> b*32768 + voxel   (window order b,d,h,w ; in-window order wd,wh,ww)
__device__ __forceinline__ int row_to_bv(int r){
    int wi = r >> 6, n = r & 63;
    int b = wi >> 9, rem = wi & 511;
    int zd = rem >> 6, yh = (rem >> 3) & 7, xw = rem & 7;
    int wz = n >> 4, wy = (n >> 2) & 3, wx = n & 3;
    int Dz = (zd<<2)+wz, Hy = (yh<<2)+wy, Wx = (xw<<2)+wx;
    return (b<<15) + (Dz<<10) + (Hy<<5) + Wx;
}
__device__ __forceinline__ int relidx(int i,int j){
    int zi=i>>4, yi=(i>>2)&3, xi=i&3;
    int zj=j>>4, yj=(j>>2)&3, xj=j&3;
    return ((zi-zj+3)*7+(yi-yj+3))*7+(xi-xj+3);
}

// ---------------- K1: dual GEMM (192->96 & 192->192) + both LayerNorms ----------------
__global__ __launch_bounds__(256) void k1_pre(const float* __restrict__ x,
    const float* __restrict__ w1, const float* __restrict__ b1,
    const float* __restrict__ g1, const float* __restrict__ bb1,
    const float* __restrict__ w2, const float* __restrict__ b2,
    const float* __restrict__ g2, const float* __restrict__ bb2,
    float* __restrict__ xa, float* __restrict__ vol)
{
    __shared__ float xs[32*192];
    __shared__ float ws[32*288];
    int tid = threadIdx.x;
    int row0 = blockIdx.x * 32;
    for(int i=tid;i<32*192;i+=256) xs[i] = x[(size_t)row0*192 + i];
    float acc[4][9]={};
    int cbase = tid & 31;
    int rbase = (tid >> 5) << 2;
    for(int k0=0;k0<192;k0+=32){
        __syncthreads();
        for(int i=tid;i<32*288;i+=256){
            int kk=i/288, cc=i-kk*288;
            int kg=k0+kk;
            ws[i] = (cc<96)? w1[kg*96+cc] : w2[kg*192+(cc-96)];
        }
        __syncthreads();
        for(int kk=0;kk<32;kk++){
            float a0=xs[(rbase+0)*192+k0+kk];
            float a1=xs[(rbase+1)*192+k0+kk];
            float a2=xs[(rbase+2)*192+k0+kk];
            float a3=xs[(rbase+3)*192+k0+kk];
            #pragma unroll
            for(int j=0;j<9;j++){
                float wv=ws[kk*288+cbase+32*j];
                acc[0][j]+=a0*wv; acc[1][j]+=a1*wv; acc[2][j]+=a2*wv; acc[3][j]+=a3*wv;
            }
        }
    }
    __syncthreads();
    #pragma unroll
    for(int a=0;a<4;a++){
        #pragma unroll
        for(int j=0;j<9;j++){
            int cc=cbase+32*j;
            ws[(rbase+a)*288+cc]=acc[a][j] + ((cc<96)? b1[cc] : b2[cc-96]);
        }
    }
    __syncthreads();
    int lr = tid>>3, part = tid&7;
    int r = row0+lr;
    // LN attention part (96)
    {
        float s=0.f, ss=0.f;
        for(int c=part*12;c<part*12+12;c++){ float v=ws[lr*288+c]; s+=v; ss+=v*v; }
        for(int o=1;o<8;o<<=1){ s+=__shfl_xor(s,o); ss+=__shfl_xor(ss,o); }
        float m=s*(1.f/96.f), var=ss*(1.f/96.f)-m*m, rstd=rsqrtf(var+EPS);
        for(int c=part*12;c<part*12+12;c++){
            xa[(size_t)r*96+c]=(ws[lr*288+c]-m)*rstd*g1[c]+bb1[c];
        }
    }
    // LN cnn part (192) -> scatter to volume (NDHWC)
    {
        float s=0.f, ss=0.f;
        for(int c=96+part*24;c<96+part*24+24;c++){ float v=ws[lr*288+c]; s+=v; ss+=v*v; }
        for(int o=1;o<8;o<<=1){ s+=__shfl_xor(s,o); ss+=__shfl_xor(ss,o); }
        float m=s*(1.f/192.f), var=ss*(1.f/192.f)-m*m, rstd=rsqrtf(var+EPS);
        int bv = row_to_bv(r);
        for(int c=part*24;c<part*24+24;c++){
            vol[(size_t)bv*192+c]=(ws[lr*288+96+c]-m)*rstd*g2[c]+bb2[c];
        }
    }
}

// ---------------- K2: depthwise 3x3x3 conv, NDHWC, slide along W ----------------
__global__ __launch_bounds__(192) void k2_dwconv(const float* __restrict__ vin,
        const float* __restrict__ wd_, const float* __restrict__ bd,
        float* __restrict__ vout)
{
    int c=threadIdx.x;
    int blk=blockIdx.x;
    int Hy=blk&31, Dz=(blk>>5)&31, b=blk>>10;
    float wreg[27];
    #pragma unroll
    for(int t=0;t<27;t++) wreg[t]=wd_[c*27+t];
    float bias=bd[c];
    const float* base=vin + ((size_t)b<<15)*192;
    int voff[9]; bool vld[9];
    #pragma unroll
    for(int i=0;i<9;i++){
        int zz=Dz+i/3-1, yy=Hy+i%3-1;
        vld[i]=(zz>=0&&zz<32&&yy>=0&&yy<32);
        voff[i]=(zz<<10)+(yy<<5);
    }
    float prv[9],cur[9],nxt[9];
    #pragma unroll
    for(int i=0;i<9;i++){
        prv[i]=0.f;
        cur[i]= vld[i]? base[(size_t)(voff[i])*192+c]   : 0.f;
        nxt[i]= vld[i]? base[(size_t)(voff[i]+1)*192+c] : 0.f;
    }
    size_t obase=((size_t)((b<<15)+(Dz<<10)+(Hy<<5)))*192 + c;
    for(int wx=0;wx<32;wx++){
        float o=bias;
        #pragma unroll
        for(int i=0;i<9;i++) o += prv[i]*wreg[i*3] + cur[i]*wreg[i*3+1] + nxt[i]*wreg[i*3+2];
        vout[obase + (size_t)wx*192] = o;
        #pragma unroll
        for(int i=0;i<9;i++){ prv[i]=cur[i]; cur[i]=nxt[i]; }
        int wn=wx+2;
        #pragma unroll
        for(int i=0;i<9;i++) nxt[i]=(vld[i]&&wn<32)? base[(size_t)(voff[i]+wn)*192+c] : 0.f;
    }
}

// ---------------- K3: instance-norm partial sums over spatial (per b,c) ----------------
__global__ __launch_bounds__(192) void k3_stats(const float* __restrict__ v,
      float* __restrict__ sum, float* __restrict__ sumsq)
{
    int c=threadIdx.x;
    int chunk=blockIdx.x, b=blockIdx.y;
    float s=0.f,ss=0.f;
    const float* p = v + (((size_t)b<<15) + (size_t)chunk*256)*192 + c;
    for(int i=0;i<256;i++){ float t=p[(size_t)i*192]; s+=t; ss+=t*t; }
    atomicAdd(&sum[b*192+c], s);
    atomicAdd(&sumsq[b*192+c], ss);
}

__global__ void k_finalize(const float* __restrict__ sum, const float* __restrict__ sumsq,
                           float* __restrict__ mean, float* __restrict__ rstd, int n, float inv)
{
    int i = blockIdx.x*blockDim.x + threadIdx.x;
    if(i<n){ float m=sum[i]*inv; float v=sumsq[i]*inv - m*m; mean[i]=m; rstd[i]=rsqrtf(v+EPS); }
}

// ---------------- K4: in-place inorm+gelu + pooled partials ----------------
__global__ __launch_bounds__(192) void k4_apply(float* __restrict__ v,
      const float* __restrict__ mean, const float* __restrict__ rstd, float* __restrict__ pooled)
{
    int c=threadIdx.x; int chunk=blockIdx.x, b=blockIdx.y;
    float m=mean[b*192+c], r=rstd[b*192+c];
    float s=0.f;
    float* p = v + (((size_t)b<<15)+(size_t)chunk*256)*192 + c;
    for(int i=0;i<256;i++){
        float t=(p[(size_t)i*192]-m)*r;
        t=gelu_f(t);
        p[(size_t)i*192]=t; s+=t;
    }
    atomicAdd(&pooled[b*192+c], s);
}

// ---------------- K4b: channel-interaction MLP -> sigmoid gate ----------------
__global__ __launch_bounds__(128) void k4b_gate(const float* __restrict__ pooled,
   const float* __restrict__ w1,const float* __restrict__ b1,
   const float* __restrict__ w2,const float* __restrict__ b2, float* __restrict__ gate)
{
    __shared__ float pm[192];
    __shared__ float h[24];
    int b=blockIdx.x, t=threadIdx.x;
    for(int i=t;i<192;i+=128) pm[i]=pooled[b*192+i]*(1.f/32768.f);
    __syncthreads();
    if(t<24){ float a=b1[t]; for(int k=0;k<192;k++) a+=pm[k]*w1[k*24+t]; h[t]=gelu_f(a); }
    __syncthreads();
    if(t<96){ float a=b2[t]; for(int j=0;j<24;j++) a+=h[j]*w2[j*96+t]; gate[b*96+t]=sigmoid_f(a); }
}

// ---------------- Kqkv: QKV GEMM (K=96), q*0.25 and v*gate folded, bf16 out ----------------
__global__ __launch_bounds__(256) void kqkv(const float* __restrict__ xa,
    const float* __restrict__ w, const float* __restrict__ bias,
    const float* __restrict__ gate, __hip_bfloat16* __restrict__ qkv)
{
    __shared__ float xs[32*96];
    __shared__ float ws[32*288];
    int tid=threadIdx.x; int row0=blockIdx.x*32;
    for(int i=tid;i<32*96;i+=256) xs[i]=xa[(size_t)row0*96+i];
    float acc[4][9]={};
    int cbase=tid&31, rbase=(tid>>5)<<2;
    for(int k0=0;k0<96;k0+=32){
        __syncthreads();
        for(int i=tid;i<32*288;i+=256){int kk=i/288,cc=i-kk*288; ws[i]=w[(k0+kk)*288+cc];}
        __syncthreads();
        for(int kk=0;kk<32;kk++){
            float a0=xs[(rbase+0)*96+k0+kk],a1=xs[(rbase+1)*96+k0+kk],
                  a2=xs[(rbase+2)*96+k0+kk],a3=xs[(rbase+3)*96+k0+kk];
            #pragma unroll
            for(int j=0;j<9;j++){
                float wv=ws[kk*288+cbase+32*j];
                acc[0][j]+=a0*wv;acc[1][j]+=a1*wv;acc[2][j]+=a2*wv;acc[3][j]+=a3*wv;
            }
        }
    }
    #pragma unroll
    for(int a=0;a<4;a++){
        int row=row0+rbase+a; int wi=row>>6, n=row&63, b=row>>15;
        #pragma unroll
        for(int j=0;j<9;j++){
            int col=cbase+32*j;
            float v=acc[a][j]+bias[col];
            int which=col/96, rem=col-which*96;
            int hh=rem>>4, e=rem&15;
            if(which==0) v*=0.25f;
            else if(which==2) v*=gate[b*96+rem];
            qkv[((size_t)(wi*18+which*6+hh)<<10) + (n<<4) + e]=__float2bfloat16(v);
        }
    }
}

// ---------------- K6: windowed attention (per window, loop heads) ----------------
__global__ __launch_bounds__(256) void k6_attn(const __hip_bfloat16* __restrict__ qkv,
    const float* __restrict__ rpb, float* __restrict__ ato)
{
    __shared__ float sq[64*QS], sk[64*QS], sv[64*QS];
    __shared__ float sS[64*SS];
    int tid=threadIdx.x;
    int wi=blockIdx.x;
    for(int h=0;h<6;h++){
        __syncthreads();
        for(int i=tid;i<3*1024;i+=256){
            int which=i>>10, r=i&1023; int n=r>>4, e=r&15;
            float val=__bfloat162float(qkv[((size_t)(wi*18+which*6+h)<<10) + r]);
            if(which==0) sq[n*QS+e]=val; else if(which==1) sk[n*QS+e]=val; else sv[n*QS+e]=val;
        }
        __syncthreads();
        {   // S = qk^T + bias : 4x4 tiles
            int ti=tid>>4, tj=tid&15;
            int i0=ti*4, j0=tj*4;
            float a[4][4]={};
            #pragma unroll
            for(int e=0;e<16;e++){
                float qv[4], kv[4];
                #pragma unroll
                for(int ii=0;ii<4;ii++) qv[ii]=sq[(i0+ii)*QS+e];
                #pragma unroll
                for(int jj=0;jj<4;jj++) kv[jj]=sk[(j0+jj)*QS+e];
                #pragma unroll
                for(int ii=0;ii<4;ii++)
                    #pragma unroll
                    for(int jj=0;jj<4;jj++) a[ii][jj]+=qv[ii]*kv[jj];
            }
            #pragma unroll
            for(int ii=0;ii<4;ii++)
                #pragma unroll
                for(int jj=0;jj<4;jj++)
                    sS[(i0+ii)*SS+j0+jj]=a[ii][jj]+rpb[relidx(i0+ii,j0+jj)*6+h];
        }
        __syncthreads();
        {   // softmax rows (4 lanes per row)
            int i=tid>>2, j0=(tid&3)<<4;
            float mx=-1e30f;
            for(int jj=0;jj<16;jj++) mx=fmaxf(mx,sS[i*SS+j0+jj]);
            for(int o=1;o<4;o<<=1) mx=fmaxf(mx,__shfl_xor(mx,o));
            float sum=0.f;
            for(int jj=0;jj<16;jj++){float p=__expf(sS[i*SS+j0+jj]-mx); sS[i*SS+j0+jj]=p; sum+=p;}
            for(int o=1;o<4;o<<=1) sum+=__shfl_xor(sum,o);
            float inv=1.f/sum;
            for(int jj=0;jj<16;jj++) sS[i*SS+j0+jj]*=inv;
        }
        __syncthreads();
        {   // O = P @ v
            int i=tid&63, e0=(tid>>6)<<2;
            float o0=0.f,o1=0.f,o2=0.f,o3=0.f;
            for(int j=0;j<64;j++){
                float p=sS[i*SS+j];
                o0+=p*sv[j*QS+e0];o1+=p*sv[j*QS+e0+1];o2+=p*sv[j*QS+e0+2];o3+=p*sv[j*QS+e0+3];
            }
            float* dst=&ato[((size_t)(wi*64+i))*96 + (h<<4) + e0];
            dst[0]=o0;dst[1]=o1;dst[2]=o2;dst[3]=o3;
        }
    }
}

// ---------------- K5: 1x1 conv 192->96 (post-gelu volume) ----------------
__global__ __launch_bounds__(256) void k5_pj(const float* __restrict__ vin,
    const float* __restrict__ w, const float* __restrict__ bias, float* __restrict__ out)
{
    __shared__ float xs[32*192];
    __shared__ float ws[32*96];
    int tid=threadIdx.x; int row0=blockIdx.x*32;
    for(int i=tid;i<32*192;i+=256) xs[i]=vin[(size_t)row0*192+i];
    float acc[4][3]={};
    int cbase=tid&31, rbase=(tid>>5)<<2;
    for(int k0=0;k0<192;k0+=32){
        __syncthreads();
        for(int i=tid;i<32*96;i+=256){ int kk=i/96, cc=i-kk*96; ws[i]=w[(k0+kk)*96+cc]; }
        __syncthreads();
        for(int kk=0;kk<32;kk++){
            float a0=xs[(rbase+0)*192+k0+kk], a1=xs[(rbase+1)*192+k0+kk],
                  a2=xs[(rbase+2)*192+k0+kk], a3=xs[(rbase+3)*192+k0+kk];
            #pragma unroll
            for(int j=0;j<3;j++){
                float wv=ws[kk*96+cbase+32*j];
                acc[0][j]+=a0*wv; acc[1][j]+=a1*wv; acc[2][j]+=a2*wv; acc[3][j]+=a3*wv;
            }
        }
    }
    #pragma unroll
    for(int a=0;a<4;a++){
        #pragma unroll
        for(int j=0;j<3;j++){
            int cc=cbase+32*j;
            out[(size_t)(row0+rbase+a)*96+cc]=acc[a][j]+bias[cc];
        }
    }
}

// ---------------- K7a: spatial-interaction conv1 (96->12) + stats ----------------
__global__ __launch_bounds__(192) void k7a_si(const float* __restrict__ ato,
    const float* __restrict__ w1, const float* __restrict__ b1,
    float* __restrict__ si12, float* __restrict__ siSum, float* __restrict__ siSumsq)
{
    __shared__ float sa[64*XAS];
    __shared__ float sw[96*12];
    __shared__ float red[24];
    int tid=threadIdx.x, wi=blockIdx.x, b=wi>>9;
    for(int i=tid;i<64*96;i+=192){ int n=i/96,c=i-n*96; sa[n*XAS+c]=ato[((size_t)(wi*64+n))*96+c]; }
    for(int i=tid;i<96*12;i+=192) sw[i]=w1[i];
    if(tid<24) red[tid]=0.f;
    __syncthreads();
    #pragma unroll
    for(int j=0;j<4;j++){
        int o=tid+192*j; int n=o/12, cc=o-n*12;
        float a=b1[cc];
        for(int k=0;k<96;k++) a+=sa[n*XAS+k]*sw[k*12+cc];
        atomicAdd(&red[cc],a);
        atomicAdd(&red[12+cc],a*a);
        int bv=row_to_bv(wi*64+n);
        si12[(size_t)bv*12+cc]=a;
    }
    __syncthreads();
    if(tid<12){ atomicAdd(&siSum[b*12+tid],red[tid]); atomicAdd(&siSumsq[b*12+tid],red[12+tid]); }
}

// ---------------- K7d: inorm+gelu on si12, conv2 (12->1), sigmoid ----------------
__global__ __launch_bounds__(256) void k7d_sig(const float* __restrict__ si12,
  const float* __restrict__ mean, const float* __restrict__ rstd,
  const float* __restrict__ w2, const float* __restrict__ b2, float* __restrict__ sig)
{
    int bv=blockIdx.x*256+threadIdx.x;
    int b=bv>>15;
    float a=b2[0];
    #pragma unroll
    for(int c=0;c<12;c++){
        float t=(si12[(size_t)bv*12+c]-mean[b*12+c])*rstd[b*12+c];
        a+=gelu_f(t)*w2[c];
    }
    sig[bv]=sigmoid_f(a);
}

// ---------------- K8: stats of sigmoid(si)*PJ (per b,c of 96) ----------------
__global__ __launch_bounds__(192) void k8_gstats(const float* __restrict__ pj,
   const float* __restrict__ sig, float* __restrict__ gSum, float* __restrict__ gSumsq)
{
    int tid=threadIdx.x; int c=tid%96, vh=tid/96;
    int chunk=blockIdx.x, b=blockIdx.y;
    float s=0.f,ss=0.f;
    for(int i=0;i<128;i++){
        int v=chunk*256 + i*2 + vh;
        int bv=(b<<15)+v;
        float t=sig[bv]*pj[(size_t)bv*96+c];
        s+=t; ss+=t*t;
    }
    atomicAdd(&gSum[b*96+c],s); atomicAdd(&gSumsq[b*96+c],ss);
}

// ---------------- K9a: LN(attn) + gated-inorm gather -> U (in d_out) ----------------
__global__ __launch_bounds__(256) void k9a_gather(const float* __restrict__ ato,
  const float* __restrict__ pj, const float* __restrict__ sig,
  const float* __restrict__ gMean, const float* __restrict__ gRstd,
  const float* __restrict__ ga, const float* __restrict__ bba,
  float* __restrict__ U)
{
    int tid=threadIdx.x; int row0=blockIdx.x*32;
    int rr=tid>>3, part=tid&7;
    int r=row0+rr;
    // LN over the 96 attention channels (8 lanes x 12)
    float av[12];
    #pragma unroll
    for(int j=0;j<12;j++) av[j]=ato[(size_t)r*96+part*12+j];
    float s=0.f, ss=0.f;
    #pragma unroll
    for(int j=0;j<12;j++){ s+=av[j]; ss+=av[j]*av[j]; }
    #pragma unroll
    for(int o=1;o<8;o<<=1){ s+=__shfl_xor(s,o); ss+=__shfl_xor(ss,o); }
    float m=s*(1.f/96.f), var=ss*(1.f/96.f)-m*m, rstd=rsqrtf(var+EPS);
    #pragma unroll
    for(int j=0;j<12;j++){
        int c=part*12+j;
        U[(size_t)r*192+c]=(av[j]-m)*rstd*ga[c]+bba[c];
    }
    // gated instance-normalized cnn half
    int bv=row_to_bv(r); int b=bv>>15;
    float sg=sig[bv];
    #pragma unroll
    for(int j=0;j<12;j++){
        int c=part*12+j;
        float t=sg*pj[(size_t)bv*96+c];
        U[(size_t)r*192+96+c]=(t-gMean[b*96+c])*gRstd[b*96+c];
    }
}

// ---------------- K9b: final 192x192 projection, in-place on d_out ----------------
__global__ __launch_bounds__(256) void k9b_gemm(const float* __restrict__ wp,
  const float* __restrict__ bp, float* __restrict__ out)
{
    __shared__ float xs[32*192];
    __shared__ float ws[32*192];
    int tid=threadIdx.x; int row0=blockIdx.x*32;
    // read the whole input tile BEFORE any store (in-place safety: blocks own disjoint rows)
    for(int i=tid;i<32*192;i+=256) xs[i]=out[(size_t)row0*192+i];
    float acc[4][6]={};
    int cbase=tid&31, rbase=(tid>>5)<<2;
    for(int k0=0;k0<192;k0+=32){
        __syncthreads();
        for(int i=tid;i<32*192;i+=256){ int kk=i/192,cc=i-kk*192; ws[i]=wp[(k0+kk)*192+cc]; }
        __syncthreads();
        for(int kk=0;kk<32;kk++){
            float a0=xs[(rbase+0)*192+k0+kk],a1=xs[(rbase+1)*192+k0+kk],
                  a2=xs[(rbase+2)*192+k0+kk],a3=xs[(rbase+3)*192+k0+kk];
            #pragma unroll
            for(int j=0;j<6;j++){
                float wv=ws[kk*192+cbase+32*j];
                acc[0][j]+=a0*wv;acc[1][j]+=a1*wv;acc[2][j]+=a2*wv;acc[3][j]+=a3*wv;
            }
        }
    }
    #pragma unroll
    for(int a=0;a<4;a++){
        #pragma unroll
        for(int j=0;j<6;j++){
            int cc=cbase+32*j;
            out[(size_t)(row0+rbase+a)*192+cc]=acc[a][j]+bp[cc];
        }
    }
}

extern "C" void kernel_launch(void* const* d_in, const int* in_sizes, int n_in,
                              void* d_out, int out_size, void* d_ws, size_t ws_size,
                              hipStream_t stream)
{
    const float* x      =(const float*)d_in[0];
    const float* w_pattn=(const float*)d_in[1];
    const float* b_pattn=(const float*)d_in[2];
    const float* g_aln  =(const float*)d_in[3];
    const float* b_aln  =(const float*)d_in[4];
    const float* w_pcnn =(const float*)d_in[5];
    const float* b_pcnn =(const float*)d_in[6];
    const float* g_cln  =(const float*)d_in[7];
    const float* b_cln  =(const float*)d_in[8];
    const float* dw_w   =(const float*)d_in[9];
    const float* dw_b   =(const float*)d_in[10];
    const float* ci_w1  =(const float*)d_in[11];
    const float* ci_b1  =(const float*)d_in[12];
    const float* ci_w2  =(const float*)d_in[13];
    const float* ci_b2  =(const float*)d_in[14];
    const float* pj_w   =(const float*)d_in[15];
    const float* pj_b   =(const float*)d_in[16];
    const float* qkv_w  =(const float*)d_in[17];
    const float* qkv_b  =(const float*)d_in[18];
    const float* si_w1  =(const float*)d_in[19];
    const float* si_b1  =(const float*)d_in[20];
    const float* si_w2  =(const float*)d_in[21];
    const float* si_b2  =(const float*)d_in[22];
    const float* g_anorm=(const float*)d_in[23];
    const float* b_anorm=(const float*)d_in[24];
    const float* w_proj =(const float*)d_in[25];
    const float* b_proj =(const float*)d_in[26];
    const float* rpb    =(const float*)d_in[27];
    (void)in_sizes; (void)n_in; (void)out_size; (void)ws_size;

    float* ws  =(float*)d_ws;
    float* vol =(float*)d_out;            // post-dwconv volume lives in d_out until k9a overwrites
    // ws float offsets:
    float* XA   = ws;                     // [0, 12,582,912)  -> later reused as ATO
    float* VOLA = ws + 12582912;          // [12,582,912, 37,748,736) : LN'd cnn volume
    __hip_bfloat16* QKV = (__hip_bfloat16*)(ws + 12582912);  // overlays dead VOLA after K2
    float* PJ   = ws + 12582912;          // overlays dead QKV after K6
    float* SI12 = ws + 25165824;          // [25,165,824, 26,738,688)
    float* SIG  = ws + 26738688;          // [26,738,688, 26,869,760)
    float* Z0   = ws + 31457280;          // zeroed accumulators (3168 floats)
    float* IN_SUM   = Z0;        float* IN_SUMSQ = Z0+768;
    float* POOLED   = Z0+1536;
    float* SI_SUM   = Z0+2304;   float* SI_SUMSQ = Z0+2352;
    float* G_SUM    = Z0+2400;   float* G_SUMSQ  = Z0+2784;
    float* NZ   = ws + 31460448;
    float* IN_MEAN  = NZ;        float* IN_RSTD  = NZ+768;
    float* GATE     = NZ+1536;
    float* SI_MEAN  = NZ+1920;   float* SI_RSTD  = NZ+1968;
    float* G_MEAN   = NZ+2016;   float* G_RSTD   = NZ+2400;

    // 1. dual GEMM + LNs
    k1_pre<<<4096,256,0,stream>>>(x,w_pattn,b_pattn,g_aln,b_aln,
                                  w_pcnn,b_pcnn,g_cln,b_cln,XA,VOLA);
    // 2. depthwise conv -> d_out
    k2_dwconv<<<4096,192,0,stream>>>(VOLA,dw_w,dw_b,vol);
    // zero accumulators (VOLA now dead; Z0 sits in its tail)
    hipMemsetAsync((void*)Z0, 0, 3168*sizeof(float), stream);
    // 3. instance norm stats + finalize
    k3_stats<<<dim3(128,4),192,0,stream>>>(vol,IN_SUM,IN_SUMSQ);
    k_finalize<<<3,256,0,stream>>>(IN_SUM,IN_SUMSQ,IN_MEAN,IN_RSTD,768,1.f/32768.f);
    // 4. in-place inorm+gelu + pooled ; gate MLP
    k4_apply<<<dim3(128,4),192,0,stream>>>(vol,IN_MEAN,IN_RSTD,POOLED);
    k4b_gate<<<4,128,0,stream>>>(POOLED,ci_w1,ci_b1,ci_w2,ci_b2,GATE);
    // 5. QKV GEMM (bf16 out, gate/scale folded)
    kqkv<<<4096,256,0,stream>>>(XA,qkv_w,qkv_b,GATE,QKV);
    // 6. attention (writes ATO over dead XA)
    k6_attn<<<2048,256,0,stream>>>(QKV,rpb,XA);
    // 7. 1x1 conv 192->96 (PJ overlays dead QKV head)
    k5_pj<<<4096,256,0,stream>>>(vol,pj_w,pj_b,PJ);
    // 8. spatial-interaction path
    k7a_si<<<2048,192,0,stream>>>(XA,si_w1,si_b1,SI12,SI_SUM,SI_SUMSQ);
    k_finalize<<<1,64,0,stream>>>(SI_SUM,SI_SUMSQ,SI_MEAN,SI_RSTD,48,1.f/32768.f);
    k7d_sig<<<512,256,0,stream>>>(SI12,SI_MEAN,SI_RSTD,si_w2,si_b2,SIG);
    // 9. gated-cnn instance norm stats
    k8_gstats<<<dim3(128,4),192,0,stream>>>(PJ,SIG,G_SUM,G_SUMSQ);
    k_finalize<<<2,256,0,stream>>>(G_SUM,G_SUMSQ,G_MEAN,G_RSTD,384,1.f/32768.f);
    // 10a. LN(attn) + gated inorm gather -> U (overwrites d_out; vol is dead after k5_pj)
    k9a_gather<<<4096,256,0,stream>>>(XA,PJ,SIG,G_MEAN,G_RSTD,
                                      g_anorm,b_anorm,vol);
    // 10b. final projection GEMM, in-place on d_out
    k9b_gemm<<<4096,256,0,stream>>>(w_proj,b_proj,vol);
}

// Round 4
// 1464.738 us; speedup vs baseline: 6.6575x; 6.5291x over previous
//
#include <hip/hip_runtime.h>
#include <hip/hip_bf16.h>
#include <math.h>

#define EPS 1e-5f
#define XAS 97
#define QS 17
#define SS 65

typedef __attribute__((ext_vector_type(8))) short short8;
typedef __attribute__((ext_vector_type(4))) float f32x4;

__device__ __forceinline__ float gelu_f(float x){
    return 0.5f*x*(1.0f+erff(x*0.7071067811865475f));
}
__device__ __forceinline__ float sigmoid_f(float x){
    return 1.0f/(1.0f+__expf(-x));
}
// row (wi*64+n) -> b*32768 + voxel   (window order b,d,h,w ; in-window order wd,wh,ww)
__device__ __forceinline__ int row_to_bv(int r){
    int wi = r >> 6, n = r & 63;
    int b = wi >> 9, rem = wi & 511;
    int zd = rem >> 6, yh = (rem >> 3) & 7, xw = rem & 7;
    int wz = n >> 4, wy = (n >> 2) & 3, wx = n & 3;
    int Dz = (zd<<2)+wz, Hy = (yh<<2)+wy, Wx = (xw<<2)+wx;
    return (b<<15) + (Dz<<10) + (Hy<<5) + Wx;
}
__device__ __forceinline__ int relidx(int i,int j){
    int zi=i>>4, yi=(i>>2)&3, xi=i&3;
    int zj=j>>4, yj=(j>>2)&3, xj=j&3;
    return ((zi-zj+3)*7+(yi-yj+3))*7+(xi-xj+3);
}

// ---------------- K1: dual GEMM (192->96 & 192->192) + both LayerNorms ----------------
__global__ __launch_bounds__(256) void k1_pre(const float* __restrict__ x,
    const float* __restrict__ w1, const float* __restrict__ b1,
    const float* __restrict__ g1, const float* __restrict__ bb1,
    const float* __restrict__ w2, const float* __restrict__ b2,
    const float* __restrict__ g2, const float* __restrict__ bb2,
    float* __restrict__ xa, float* __restrict__ vol)
{
    __shared__ float xs[32*192];
    __shared__ float ws[32*288];
    int tid = threadIdx.x;
    int row0 = blockIdx.x * 32;
    for(int i=tid;i<32*192;i+=256) xs[i] = x[(size_t)row0*192 + i];
    float acc[4][9]={};
    int cbase = tid & 31;
    int rbase = (tid >> 5) << 2;
    for(int k0=0;k0<192;k0+=32){
        __syncthreads();
        for(int i=tid;i<32*288;i+=256){
            int kk=i/288, cc=i-kk*288;
            int kg=k0+kk;
            ws[i] = (cc<96)? w1[kg*96+cc] : w2[kg*192+(cc-96)];
        }
        __syncthreads();
        for(int kk=0;kk<32;kk++){
            float a0=xs[(rbase+0)*192+k0+kk];
            float a1=xs[(rbase+1)*192+k0+kk];
            float a2=xs[(rbase+2)*192+k0+kk];
            float a3=xs[(rbase+3)*192+k0+kk];
            #pragma unroll
            for(int j=0;j<9;j++){
                float wv=ws[kk*288+cbase+32*j];
                acc[0][j]+=a0*wv; acc[1][j]+=a1*wv; acc[2][j]+=a2*wv; acc[3][j]+=a3*wv;
            }
        }
    }
    __syncthreads();
    #pragma unroll
    for(int a=0;a<4;a++){
        #pragma unroll
        for(int j=0;j<9;j++){
            int cc=cbase+32*j;
            ws[(rbase+a)*288+cc]=acc[a][j] + ((cc<96)? b1[cc] : b2[cc-96]);
        }
    }
    __syncthreads();
    int lr = tid>>3, part = tid&7;
    int r = row0+lr;
    // LN attention part (96)
    {
        float s=0.f, ss=0.f;
        for(int c=part*12;c<part*12+12;c++){ float v=ws[lr*288+c]; s+=v; ss+=v*v; }
        for(int o=1;o<8;o<<=1){ s+=__shfl_xor(s,o); ss+=__shfl_xor(ss,o); }
        float m=s*(1.f/96.f), var=ss*(1.f/96.f)-m*m, rstd=rsqrtf(var+EPS);
        for(int c=part*12;c<part*12+12;c++){
            xa[(size_t)r*96+c]=(ws[lr*288+c]-m)*rstd*g1[c]+bb1[c];
        }
    }
    // LN cnn part (192) -> scatter to volume (NDHWC)
    {
        float s=0.f, ss=0.f;
        for(int c=96+part*24;c<96+part*24+24;c++){ float v=ws[lr*288+c]; s+=v; ss+=v*v; }
        for(int o=1;o<8;o<<=1){ s+=__shfl_xor(s,o); ss+=__shfl_xor(ss,o); }
        float m=s*(1.f/192.f), var=ss*(1.f/192.f)-m*m, rstd=rsqrtf(var+EPS);
        int bv = row_to_bv(r);
        for(int c=part*24;c<part*24+24;c++){
            vol[(size_t)bv*192+c]=(ws[lr*288+96+c]-m)*rstd*g2[c]+bb2[c];
        }
    }
}

// ---------------- K2: depthwise 3x3x3 conv, NDHWC, slide along W ----------------
__global__ __launch_bounds__(192) void k2_dwconv(const float* __restrict__ vin,
        const float* __restrict__ wd_, const float* __restrict__ bd,
        float* __restrict__ vout)
{
    int c=threadIdx.x;
    int blk=blockIdx.x;
    int Hy=blk&31, Dz=(blk>>5)&31, b=blk>>10;
    float wreg[27];
    #pragma unroll
    for(int t=0;t<27;t++) wreg[t]=wd_[c*27+t];
    float bias=bd[c];
    const float* base=vin + ((size_t)b<<15)*192;
    int voff[9]; bool vld[9];
    #pragma unroll
    for(int i=0;i<9;i++){
        int zz=Dz+i/3-1, yy=Hy+i%3-1;
        vld[i]=(zz>=0&&zz<32&&yy>=0&&yy<32);
        voff[i]=(zz<<10)+(yy<<5);
    }
    float prv[9],cur[9],nxt[9];
    #pragma unroll
    for(int i=0;i<9;i++){
        prv[i]=0.f;
        cur[i]= vld[i]? base[(size_t)(voff[i])*192+c]   : 0.f;
        nxt[i]= vld[i]? base[(size_t)(voff[i]+1)*192+c] : 0.f;
    }
    size_t obase=((size_t)((b<<15)+(Dz<<10)+(Hy<<5)))*192 + c;
    for(int wx=0;wx<32;wx++){
        float o=bias;
        #pragma unroll
        for(int i=0;i<9;i++) o += prv[i]*wreg[i*3] + cur[i]*wreg[i*3+1] + nxt[i]*wreg[i*3+2];
        vout[obase + (size_t)wx*192] = o;
        #pragma unroll
        for(int i=0;i<9;i++){ prv[i]=cur[i]; cur[i]=nxt[i]; }
        int wn=wx+2;
        #pragma unroll
        for(int i=0;i<9;i++) nxt[i]=(vld[i]&&wn<32)? base[(size_t)(voff[i]+wn)*192+c] : 0.f;
    }
}

// ---------------- K3: instance-norm partial sums over spatial (per b,c) ----------------
__global__ __launch_bounds__(192) void k3_stats(const float* __restrict__ v,
      float* __restrict__ sum, float* __restrict__ sumsq)
{
    int c=threadIdx.x;
    int chunk=blockIdx.x, b=blockIdx.y;
    float s=0.f,ss=0.f;
    const float* p = v + (((size_t)b<<15) + (size_t)chunk*256)*192 + c;
    for(int i=0;i<256;i++){ float t=p[(size_t)i*192]; s+=t; ss+=t*t; }
    atomicAdd(&sum[b*192+c], s);
    atomicAdd(&sumsq[b*192+c], ss);
}

__global__ void k_finalize(const float* __restrict__ sum, const float* __restrict__ sumsq,
                           float* __restrict__ mean, float* __restrict__ rstd, int n, float inv)
{
    int i = blockIdx.x*blockDim.x + threadIdx.x;
    if(i<n){ float m=sum[i]*inv; float v=sumsq[i]*inv - m*m; mean[i]=m; rstd[i]=rsqrtf(v+EPS); }
}

// ---------------- K4: in-place inorm+gelu + pooled partials ----------------
__global__ __launch_bounds__(192) void k4_apply(float* __restrict__ v,
      const float* __restrict__ mean, const float* __restrict__ rstd, float* __restrict__ pooled)
{
    int c=threadIdx.x; int chunk=blockIdx.x, b=blockIdx.y;
    float m=mean[b*192+c], r=rstd[b*192+c];
    float s=0.f;
    float* p = v + (((size_t)b<<15)+(size_t)chunk*256)*192 + c;
    for(int i=0;i<256;i++){
        float t=(p[(size_t)i*192]-m)*r;
        t=gelu_f(t);
        p[(size_t)i*192]=t; s+=t;
    }
    atomicAdd(&pooled[b*192+c], s);
}

// ---------------- K4b: channel-interaction MLP -> sigmoid gate ----------------
__global__ __launch_bounds__(128) void k4b_gate(const float* __restrict__ pooled,
   const float* __restrict__ w1,const float* __restrict__ b1,
   const float* __restrict__ w2,const float* __restrict__ b2, float* __restrict__ gate)
{
    __shared__ float pm[192];
    __shared__ float h[24];
    int b=blockIdx.x, t=threadIdx.x;
    for(int i=t;i<192;i+=128) pm[i]=pooled[b*192+i]*(1.f/32768.f);
    __syncthreads();
    if(t<24){ float a=b1[t]; for(int k=0;k<192;k++) a+=pm[k]*w1[k*24+t]; h[t]=gelu_f(a); }
    __syncthreads();
    if(t<96){ float a=b2[t]; for(int j=0;j<24;j++) a+=h[j]*w2[j*96+t]; gate[b*96+t]=sigmoid_f(a); }
}

// ---------------- Kqkv: QKV GEMM (K=96), q*0.25 and v*gate folded, bf16 out ----------------
__global__ __launch_bounds__(256) void kqkv(const float* __restrict__ xa,
    const float* __restrict__ w, const float* __restrict__ bias,
    const float* __restrict__ gate, __hip_bfloat16* __restrict__ qkv)
{
    __shared__ float xs[32*96];
    __shared__ float ws[32*288];
    int tid=threadIdx.x; int row0=blockIdx.x*32;
    for(int i=tid;i<32*96;i+=256) xs[i]=xa[(size_t)row0*96+i];
    float acc[4][9]={};
    int cbase=tid&31, rbase=(tid>>5)<<2;
    for(int k0=0;k0<96;k0+=32){
        __syncthreads();
        for(int i=tid;i<32*288;i+=256){int kk=i/288,cc=i-kk*288; ws[i]=w[(k0+kk)*288+cc];}
        __syncthreads();
        for(int kk=0;kk<32;kk++){
            float a0=xs[(rbase+0)*96+k0+kk],a1=xs[(rbase+1)*96+k0+kk],
                  a2=xs[(rbase+2)*96+k0+kk],a3=xs[(rbase+3)*96+k0+kk];
            #pragma unroll
            for(int j=0;j<9;j++){
                float wv=ws[kk*288+cbase+32*j];
                acc[0][j]+=a0*wv;acc[1][j]+=a1*wv;acc[2][j]+=a2*wv;acc[3][j]+=a3*wv;
            }
        }
    }
    #pragma unroll
    for(int a=0;a<4;a++){
        int row=row0+rbase+a; int wi=row>>6, n=row&63, b=row>>15;
        #pragma unroll
        for(int j=0;j<9;j++){
            int col=cbase+32*j;
            float v=acc[a][j]+bias[col];
            int which=col/96, rem=col-which*96;
            int hh=rem>>4, e=rem&15;
            if(which==0) v*=0.25f;
            else if(which==2) v*=gate[b*96+rem];
            qkv[((size_t)(wi*18+which*6+hh)<<10) + (n<<4) + e]=__float2bfloat16(v);
        }
    }
}

// ---------------- K6: windowed attention (per window, loop heads) ----------------
__global__ __launch_bounds__(256) void k6_attn(const __hip_bfloat16* __restrict__ qkv,
    const float* __restrict__ rpb, float* __restrict__ ato)
{
    __shared__ float sq[64*QS], sk[64*QS], sv[64*QS];
    __shared__ float sS[64*SS];
    int tid=threadIdx.x;
    int wi=blockIdx.x;
    for(int h=0;h<6;h++){
        __syncthreads();
        for(int i=tid;i<3*1024;i+=256){
            int which=i>>10, r=i&1023; int n=r>>4, e=r&15;
            float val=__bfloat162float(qkv[((size_t)(wi*18+which*6+h)<<10) + r]);
            if(which==0) sq[n*QS+e]=val; else if(which==1) sk[n*QS+e]=val; else sv[n*QS+e]=val;
        }
        __syncthreads();
        {   // S = qk^T + bias : 4x4 tiles
            int ti=tid>>4, tj=tid&15;
            int i0=ti*4, j0=tj*4;
            float a[4][4]={};
            #pragma unroll
            for(int e=0;e<16;e++){
                float qv[4], kv[4];
                #pragma unroll
                for(int ii=0;ii<4;ii++) qv[ii]=sq[(i0+ii)*QS+e];
                #pragma unroll
                for(int jj=0;jj<4;jj++) kv[jj]=sk[(j0+jj)*QS+e];
                #pragma unroll
                for(int ii=0;ii<4;ii++)
                    #pragma unroll
                    for(int jj=0;jj<4;jj++) a[ii][jj]+=qv[ii]*kv[jj];
            }
            #pragma unroll
            for(int ii=0;ii<4;ii++)
                #pragma unroll
                for(int jj=0;jj<4;jj++)
                    sS[(i0+ii)*SS+j0+jj]=a[ii][jj]+rpb[relidx(i0+ii,j0+jj)*6+h];
        }
        __syncthreads();
        {   // softmax rows (4 lanes per row)
            int i=tid>>2, j0=(tid&3)<<4;
            float mx=-1e30f;
            for(int jj=0;jj<16;jj++) mx=fmaxf(mx,sS[i*SS+j0+jj]);
            for(int o=1;o<4;o<<=1) mx=fmaxf(mx,__shfl_xor(mx,o));
            float sum=0.f;
            for(int jj=0;jj<16;jj++){float p=__expf(sS[i*SS+j0+jj]-mx); sS[i*SS+j0+jj]=p; sum+=p;}
            for(int o=1;o<4;o<<=1) sum+=__shfl_xor(sum,o);
            float inv=1.f/sum;
            for(int jj=0;jj<16;jj++) sS[i*SS+j0+jj]*=inv;
        }
        __syncthreads();
        {   // O = P @ v
            int i=tid&63, e0=(tid>>6)<<2;
            float o0=0.f,o1=0.f,o2=0.f,o3=0.f;
            for(int j=0;j<64;j++){
                float p=sS[i*SS+j];
                o0+=p*sv[j*QS+e0];o1+=p*sv[j*QS+e0+1];o2+=p*sv[j*QS+e0+2];o3+=p*sv[j*QS+e0+3];
            }
            float* dst=&ato[((size_t)(wi*64+i))*96 + (h<<4) + e0];
            dst[0]=o0;dst[1]=o1;dst[2]=o2;dst[3]=o3;
        }
    }
}

// ---------------- K5: 1x1 conv 192->96 (post-gelu volume) ----------------
__global__ __launch_bounds__(256) void k5_pj(const float* __restrict__ vin,
    const float* __restrict__ w, const float* __restrict__ bias, float* __restrict__ out)
{
    __shared__ float xs[32*192];
    __shared__ float ws[32*96];
    int tid=threadIdx.x; int row0=blockIdx.x*32;
    for(int i=tid;i<32*192;i+=256) xs[i]=vin[(size_t)row0*192+i];
    float acc[4][3]={};
    int cbase=tid&31, rbase=(tid>>5)<<2;
    for(int k0=0;k0<192;k0+=32){
        __syncthreads();
        for(int i=tid;i<32*96;i+=256){ int kk=i/96, cc=i-kk*96; ws[i]=w[(k0+kk)*96+cc]; }
        __syncthreads();
        for(int kk=0;kk<32;kk++){
            float a0=xs[(rbase+0)*192+k0+kk], a1=xs[(rbase+1)*192+k0+kk],
                  a2=xs[(rbase+2)*192+k0+kk], a3=xs[(rbase+3)*192+k0+kk];
            #pragma unroll
            for(int j=0;j<3;j++){
                float wv=ws[kk*96+cbase+32*j];
                acc[0][j]+=a0*wv; acc[1][j]+=a1*wv; acc[2][j]+=a2*wv; acc[3][j]+=a3*wv;
            }
        }
    }
    #pragma unroll
    for(int a=0;a<4;a++){
        #pragma unroll
        for(int j=0;j<3;j++){
            int cc=cbase+32*j;
            out[(size_t)(row0+rbase+a)*96+cc]=acc[a][j]+bias[cc];
        }
    }
}

// ---------------- K7a: spatial-interaction conv1 (96->12) + stats ----------------
__global__ __launch_bounds__(192) void k7a_si(const float* __restrict__ ato,
    const float* __restrict__ w1, const float* __restrict__ b1,
    float* __restrict__ si12, float* __restrict__ siSum, float* __restrict__ siSumsq)
{
    __shared__ float sa[64*XAS];
    __shared__ float sw[96*12];
    __shared__ float red[24];
    int tid=threadIdx.x, wi=blockIdx.x, b=wi>>9;
    for(int i=tid;i<64*96;i+=192){ int n=i/96,c=i-n*96; sa[n*XAS+c]=ato[((size_t)(wi*64+n))*96+c]; }
    for(int i=tid;i<96*12;i+=192) sw[i]=w1[i];
    if(tid<24) red[tid]=0.f;
    __syncthreads();
    #pragma unroll
    for(int j=0;j<4;j++){
        int o=tid+192*j; int n=o/12, cc=o-n*12;
        float a=b1[cc];
        for(int k=0;k<96;k++) a+=sa[n*XAS+k]*sw[k*12+cc];
        atomicAdd(&red[cc],a);
        atomicAdd(&red[12+cc],a*a);
        int bv=row_to_bv(wi*64+n);
        si12[(size_t)bv*12+cc]=a;
    }
    __syncthreads();
    if(tid<12){ atomicAdd(&siSum[b*12+tid],red[tid]); atomicAdd(&siSumsq[b*12+tid],red[12+tid]); }
}

// ---------------- K7d: inorm+gelu on si12, conv2 (12->1), sigmoid ----------------
__global__ __launch_bounds__(256) void k7d_sig(const float* __restrict__ si12,
  const float* __restrict__ mean, const float* __restrict__ rstd,
  const float* __restrict__ w2, const float* __restrict__ b2, float* __restrict__ sig)
{
    int bv=blockIdx.x*256+threadIdx.x;
    int b=bv>>15;
    float a=b2[0];
    #pragma unroll
    for(int c=0;c<12;c++){
        float t=(si12[(size_t)bv*12+c]-mean[b*12+c])*rstd[b*12+c];
        a+=gelu_f(t)*w2[c];
    }
    sig[bv]=sigmoid_f(a);
}

// ---------------- K8: stats of sigmoid(si)*PJ (per b,c of 96) ----------------
__global__ __launch_bounds__(192) void k8_gstats(const float* __restrict__ pj,
   const float* __restrict__ sig, float* __restrict__ gSum, float* __restrict__ gSumsq)
{
    int tid=threadIdx.x; int c=tid%96, vh=tid/96;
    int chunk=blockIdx.x, b=blockIdx.y;
    float s=0.f,ss=0.f;
    for(int i=0;i<128;i++){
        int v=chunk*256 + i*2 + vh;
        int bv=(b<<15)+v;
        float t=sig[bv]*pj[(size_t)bv*96+c];
        s+=t; ss+=t*t;
    }
    atomicAdd(&gSum[b*96+c],s); atomicAdd(&gSumsq[b*96+c],ss);
}

// ---------------- Kprep: w_proj (192x192 f32, [k][n]) -> WT bf16 [n][k] ----------------
__global__ __launch_bounds__(256) void kprep(const float* __restrict__ wp,
                                             __hip_bfloat16* __restrict__ WT)
{
    int i=blockIdx.x*256+threadIdx.x;     // 36864 total
    int n=i/192, k=i-n*192;
    WT[n*192+k]=__float2bfloat16(wp[k*192+n]);
}

// ---------------- K9a2: LN(attn) + gated-inorm -> U (bf16, in-place over ATO) ----------------
// Row r: reads ato[r*96 .. r*96+96) (f32, 384B) and writes U row r as 192 bf16 over the
// SAME 384 bytes. The 8 lanes owning a row are in one wave; all f32 loads are issued
// before any bf16 store in program order -> wave-lockstep safe.
__global__ __launch_bounds__(256) void k9a2_gather(float* atoU,
  const float* __restrict__ pj, const float* __restrict__ sig,
  const float* __restrict__ gMean, const float* __restrict__ gRstd,
  const float* __restrict__ ga, const float* __restrict__ bba)
{
    int tid=threadIdx.x; int row0=blockIdx.x*32;
    int rr=tid>>3, part=tid&7;
    int r=row0+rr;
    __hip_bfloat16* U=(__hip_bfloat16*)atoU;
    float av[12];
    #pragma unroll
    for(int j=0;j<12;j++) av[j]=atoU[(size_t)r*96+part*12+j];
    float s=0.f, ss=0.f;
    #pragma unroll
    for(int j=0;j<12;j++){ s+=av[j]; ss+=av[j]*av[j]; }
    #pragma unroll
    for(int o=1;o<8;o<<=1){ s+=__shfl_xor(s,o); ss+=__shfl_xor(ss,o); }
    float m=s*(1.f/96.f), var=ss*(1.f/96.f)-m*m, rstd=rsqrtf(var+EPS);
    // gated instance-normalized cnn half: compute BEFORE overwriting (pj is a separate buffer)
    int bv=row_to_bv(r); int b=bv>>15;
    float sg=sig[bv];
    float cv[12];
    #pragma unroll
    for(int j=0;j<12;j++){
        int c=part*12+j;
        float t=sg*pj[(size_t)bv*96+c];
        cv[j]=(t-gMean[b*96+c])*gRstd[b*96+c];
    }
    #pragma unroll
    for(int j=0;j<12;j++){
        int c=part*12+j;
        U[(size_t)r*192+c]=__float2bfloat16((av[j]-m)*rstd*ga[c]+bba[c]);
    }
    #pragma unroll
    for(int j=0;j<12;j++){
        int c=part*12+j;
        U[(size_t)r*192+96+c]=__float2bfloat16(cv[j]);
    }
}

// ---------------- K9b: final 192x192 projection via bf16 MFMA (no LDS, no barriers) ----------------
// C[m][n] = sum_k U[m][k] * WT[n][k]  (gemm_bt convention).
// Frags: A row m=lane&15 of U, B row n=lane&15 of WT, 8 contiguous k at quad*8.
// C/D: col=lane&15 (n), row=quad*4+reg (m).
__global__ __launch_bounds__(256) void k9b_mfma(const __hip_bfloat16* __restrict__ Ubf,
   const __hip_bfloat16* __restrict__ WT, const float* __restrict__ bp,
   float* __restrict__ out)
{
    int tid=threadIdx.x;
    int wave=tid>>6, lane=tid&63;
    int quad=lane>>4, l16=lane&15;
    int rowA = blockIdx.x*64 + wave*16 + l16;
    const short* Us=(const short*)Ubf;
    const short* Ws=(const short*)WT;
    f32x4 acc[12];
    #pragma unroll
    for(int j=0;j<12;j++) acc[j]=(f32x4){0.f,0.f,0.f,0.f};
    #pragma unroll
    for(int t=0;t<6;t++){
        int k0=t*32;
        short8 a = *(const short8*)(Us + (size_t)rowA*192 + k0 + quad*8);
        #pragma unroll
        for(int j=0;j<12;j++){
            short8 bfr = *(const short8*)(Ws + (size_t)(j*16+l16)*192 + k0 + quad*8);
            acc[j]=__builtin_amdgcn_mfma_f32_16x16x32_bf16(a,bfr,acc[j],0,0,0);
        }
    }
    int mbase = blockIdx.x*64 + wave*16 + quad*4;
    #pragma unroll
    for(int j=0;j<12;j++){
        int n=j*16+l16;
        float bias=bp[n];
        #pragma unroll
        for(int r2=0;r2<4;r2++){
            out[(size_t)(mbase+r2)*192 + n] = acc[j][r2] + bias;
        }
    }
}

extern "C" void kernel_launch(void* const* d_in, const int* in_sizes, int n_in,
                              void* d_out, int out_size, void* d_ws, size_t ws_size,
                              hipStream_t stream)
{
    const float* x      =(const float*)d_in[0];
    const float* w_pattn=(const float*)d_in[1];
    const float* b_pattn=(const float*)d_in[2];
    const float* g_aln  =(const float*)d_in[3];
    const float* b_aln  =(const float*)d_in[4];
    const float* w_pcnn =(const float*)d_in[5];
    const float* b_pcnn =(const float*)d_in[6];
    const float* g_cln  =(const float*)d_in[7];
    const float* b_cln  =(const float*)d_in[8];
    const float* dw_w   =(const float*)d_in[9];
    const float* dw_b   =(const float*)d_in[10];
    const float* ci_w1  =(const float*)d_in[11];
    const float* ci_b1  =(const float*)d_in[12];
    const float* ci_w2  =(const float*)d_in[13];
    const float* ci_b2  =(const float*)d_in[14];
    const float* pj_w   =(const float*)d_in[15];
    const float* pj_b   =(const float*)d_in[16];
    const float* qkv_w  =(const float*)d_in[17];
    const float* qkv_b  =(const float*)d_in[18];
    const float* si_w1  =(const float*)d_in[19];
    const float* si_b1  =(const float*)d_in[20];
    const float* si_w2  =(const float*)d_in[21];
    const float* si_b2  =(const float*)d_in[22];
    const float* g_anorm=(const float*)d_in[23];
    const float* b_anorm=(const float*)d_in[24];
    const float* w_proj =(const float*)d_in[25];
    const float* b_proj =(const float*)d_in[26];
    const float* rpb    =(const float*)d_in[27];
    (void)in_sizes; (void)n_in; (void)out_size; (void)ws_size;

    float* ws  =(float*)d_ws;
    float* vol =(float*)d_out;            // volume lives in d_out until k9b_mfma overwrites
    // ws float offsets. NOTE: QKV (bf16) spans float slots [12,582,912, 31,457,280) —
    // anything overlapping that range must be written AFTER k6_attn (QKV death).
    float* XA   = ws;                     // [0, 12,582,912)  -> ATO after k6 -> U (bf16) after k9a2
    float* VOLA = ws + 12582912;          // LN'd cnn volume (dead after k2)
    __hip_bfloat16* QKV = (__hip_bfloat16*)(ws + 12582912);  // overlays dead VOLA after K2
    float* PJ   = ws + 12582912;          // overlays dead QKV after K6
    float* SI12 = ws + 25165824;          // [25,165,824, 26,738,688) (written at k7a, after k6)
    float* SIG  = ws + 26738688;          // [26,738,688, 26,869,760)
    __hip_bfloat16* WT = (__hip_bfloat16*)(ws + 25165824); // overlays SI12 AFTER k7d_sig (18,432 float slots)
    float* Z0   = ws + 31457280;          // zeroed accumulators (3168 floats)
    float* IN_SUM   = Z0;        float* IN_SUMSQ = Z0+768;
    float* POOLED   = Z0+1536;
    float* SI_SUM   = Z0+2304;   float* SI_SUMSQ = Z0+2352;
    float* G_SUM    = Z0+2400;   float* G_SUMSQ  = Z0+2784;
    float* NZ   = ws + 31460448;
    float* IN_MEAN  = NZ;        float* IN_RSTD  = NZ+768;
    float* GATE     = NZ+1536;
    float* SI_MEAN  = NZ+1920;   float* SI_RSTD  = NZ+1968;
    float* G_MEAN   = NZ+2016;   float* G_RSTD   = NZ+2400;

    // 1. dual GEMM + LNs
    k1_pre<<<4096,256,0,stream>>>(x,w_pattn,b_pattn,g_aln,b_aln,
                                  w_pcnn,b_pcnn,g_cln,b_cln,XA,VOLA);
    // 2. depthwise conv -> d_out
    k2_dwconv<<<4096,192,0,stream>>>(VOLA,dw_w,dw_b,vol);
    // zero accumulators (VOLA now dead; Z0 sits past QKV's end)
    hipMemsetAsync((void*)Z0, 0, 3168*sizeof(float), stream);
    // 3. instance norm stats + finalize
    k3_stats<<<dim3(128,4),192,0,stream>>>(vol,IN_SUM,IN_SUMSQ);
    k_finalize<<<3,256,0,stream>>>(IN_SUM,IN_SUMSQ,IN_MEAN,IN_RSTD,768,1.f/32768.f);
    // 4. in-place inorm+gelu + pooled ; gate MLP
    k4_apply<<<dim3(128,4),192,0,stream>>>(vol,IN_MEAN,IN_RSTD,POOLED);
    k4b_gate<<<4,128,0,stream>>>(POOLED,ci_w1,ci_b1,ci_w2,ci_b2,GATE);
    // 5. QKV GEMM (bf16 out, gate/scale folded)
    kqkv<<<4096,256,0,stream>>>(XA,qkv_w,qkv_b,GATE,QKV);
    // 6. attention (writes ATO over dead XA)
    k6_attn<<<2048,256,0,stream>>>(QKV,rpb,XA);
    // 7. 1x1 conv 192->96 (PJ overlays dead QKV head)
    k5_pj<<<4096,256,0,stream>>>(vol,pj_w,pj_b,PJ);
    // 8. spatial-interaction path
    k7a_si<<<2048,192,0,stream>>>(XA,si_w1,si_b1,SI12,SI_SUM,SI_SUMSQ);
    k_finalize<<<1,64,0,stream>>>(SI_SUM,SI_SUMSQ,SI_MEAN,SI_RSTD,48,1.f/32768.f);
    k7d_sig<<<512,256,0,stream>>>(SI12,SI_MEAN,SI_RSTD,si_w2,si_b2,SIG);
    // weight transpose/cast for the final MFMA GEMM (overlays SI12, which is now dead)
    kprep<<<144,256,0,stream>>>(w_proj,WT);
    // 9. gated-cnn instance norm stats
    k8_gstats<<<dim3(128,4),192,0,stream>>>(PJ,SIG,G_SUM,G_SUMSQ);
    k_finalize<<<2,256,0,stream>>>(G_SUM,G_SUMSQ,G_MEAN,G_RSTD,384,1.f/32768.f);
    // 10a. LN(attn) + gated inorm -> U bf16, in-place over ATO (ws). d_out untouched.
    k9a2_gather<<<4096,256,0,stream>>>(XA,PJ,SIG,G_MEAN,G_RSTD,g_anorm,b_anorm);
    // 10b. final projection GEMM via MFMA -> d_out (only epilogue stores touch d_out)
    k9b_mfma<<<2048,256,0,stream>>>((const __hip_bfloat16*)XA,WT,b_proj,vol);
}